// Round 1
// baseline (188.975 us; speedup 1.0000x reference)
//
#include <hip/hip_runtime.h>
#include <math.h>

#define BB 64
#define TT 4096
#define DD 256
#define HH 256
#define NEG_INF_F (-1e9f)

// ws layout (in floats):
//   meansum : [BB*DD]        @ 0
//   wkq     : [BB*DD]        @ 16384
//   ek      : [BB]           @ 32768
//   suma    : [BB]           @ 32832
//   e       : [BB*TT]        @ 32896
//   supp    : [BB*TT] (int)  @ 32896 + BB*TT
//   count   : [BB]    (int)  @ 32896 + 2*BB*TT
// total ~2.23 MB

// ---------------- Kernel 1: column sums over T (for mean) -------------------
__global__ __launch_bounds__(256) void k_colsum(const float* __restrict__ input,
                                                float* __restrict__ meansum) {
    int b = blockIdx.x;
    int chunk = blockIdx.y;              // 32 chunks of 128 t each
    int tid = threadIdx.x;
    int tsub = tid >> 6;                 // 0..3
    int d4 = tid & 63;                   // float4 index over D
    const float4* base = (const float4*)(input + ((size_t)b * TT + (size_t)chunk * 128) * DD);
    float4 acc = make_float4(0.f, 0.f, 0.f, 0.f);
    for (int t = tsub; t < 128; t += 4) {
        float4 v = base[(size_t)t * 64 + d4];
        acc.x += v.x; acc.y += v.y; acc.z += v.z; acc.w += v.w;
    }
    __shared__ float4 sm[256];
    sm[tid] = acc;
    __syncthreads();
    if (tid < 64) {
        float4 a0 = sm[tid], a1 = sm[tid + 64], a2 = sm[tid + 128], a3 = sm[tid + 192];
        atomicAdd(&meansum[b * DD + tid * 4 + 0], a0.x + a1.x + a2.x + a3.x);
        atomicAdd(&meansum[b * DD + tid * 4 + 1], a0.y + a1.y + a2.y + a3.y);
        atomicAdd(&meansum[b * DD + tid * 4 + 2], a0.z + a1.z + a2.z + a3.z);
        atomicAdd(&meansum[b * DD + tid * 4 + 3], a0.w + a1.w + a2.w + a3.w);
    }
}

// ------------- Kernel 2: q = mean@Wq+bq ; wkq = Wk@q ; ek = bk.q ------------
__global__ __launch_bounds__(256) void k_small(const float* __restrict__ meansum,
                                               const float* __restrict__ Wq,
                                               const float* __restrict__ bq,
                                               const float* __restrict__ Wk,
                                               const float* __restrict__ bk,
                                               float* __restrict__ wkq,
                                               float* __restrict__ ek) {
    int b = blockIdx.x, tid = threadIdx.x;
    __shared__ float mr[DD];
    __shared__ float qsh[HH];
    mr[tid] = meansum[b * DD + tid] * (1.0f / (float)TT);
    __syncthreads();
    float acc = bq[tid];
    for (int d = 0; d < DD; ++d) acc += mr[d] * Wq[d * HH + tid];
    qsh[tid] = acc;
    __syncthreads();
    float w = 0.f;
    for (int h = 0; h < HH; ++h) w += Wk[tid * HH + h] * qsh[h];
    wkq[b * DD + tid] = w;
    // ek = dot(bk, q)
    float p = bk[tid] * qsh[tid];
    __syncthreads();
    mr[tid] = p;
    __syncthreads();
    for (int s = 128; s > 0; s >>= 1) {
        if (tid < s) mr[tid] += mr[tid + s];
        __syncthreads();
    }
    if (tid == 0) ek[b] = mr[0];
}

// --------- Kernel 3: e[b,t] = input.wkq + ek, time-miss, mask ---------------
__global__ __launch_bounds__(256) void k_scores(const float* __restrict__ input,
                                                const float* __restrict__ wkq,
                                                const float* __restrict__ ek,
                                                const int* __restrict__ mask,
                                                const float* __restrict__ rate,
                                                float* __restrict__ e_out) {
    int gid0 = blockIdx.x * 4;           // 4 rows per block (one per wave)
    int b = gid0 >> 12;                  // T = 4096 rows per b
    int tid = threadIdx.x;
    __shared__ float wsh[DD];
    wsh[tid] = wkq[b * DD + tid];
    __syncthreads();
    int wave = tid >> 6, lane = tid & 63;
    int gid = gid0 + wave;
    const float4* row = (const float4*)(input + (size_t)gid * DD);
    float4 v = row[lane];
    float4 w = ((const float4*)wsh)[lane];
    float sum = v.x * w.x + v.y * w.y + v.z * w.z + v.w * w.w;
#pragma unroll
    for (int off = 32; off > 0; off >>= 1) sum += __shfl_down(sum, off);
    if (lane == 0) {
        float e = sum + ek[b];
        int m = mask[gid];
        if (m != 0) {
            float sg = 1.f / (1.f + expf(e));      // = (1 - sigmoid(e))
            e = e - rate[gid & (TT - 1)] * log1pf(sg * (float)m);
        } else {
            e = NEG_INF_F;
        }
        e_out[gid] = e;
    }
}

// --------------- Kernel 4: sparsemax per row via tau bisection --------------
__global__ __launch_bounds__(1024) void k_sparsemax(const float* __restrict__ e_in,
                                                    float* __restrict__ a_out,
                                                    int* __restrict__ supp,
                                                    int* __restrict__ count,
                                                    float* __restrict__ suma) {
    int b = blockIdx.x, tid = threadIdx.x;
    __shared__ float z[TT];
    __shared__ float red[16];
    __shared__ float bcast;
    __shared__ int cnt;
    const float* er = e_in + (size_t)b * TT;
    float lmax = -3.4e38f;
    for (int i = tid; i < TT; i += 1024) {
        float v = er[i];
        z[i] = v;
        lmax = fmaxf(lmax, v);
    }
#pragma unroll
    for (int off = 32; off > 0; off >>= 1) lmax = fmaxf(lmax, __shfl_xor(lmax, off));
    int wid = tid >> 6, lane = tid & 63;
    if (lane == 0) red[wid] = lmax;
    if (tid == 0) cnt = 0;
    __syncthreads();
    if (tid == 0) {
        float m = red[0];
        for (int i = 1; i < 16; ++i) m = fmaxf(m, red[i]);
        bcast = m;
    }
    __syncthreads();
    float mx = bcast;
    for (int i = tid; i < TT; i += 1024) z[i] -= mx;
    __syncthreads();
    // tau in [zmax-1, zmax] = [-1, 0]; f(tau) = sum(max(0, z - tau)) is
    // strictly decreasing; solve f(tau) = 1.
    float lo = -1.f, hi = 0.f;
    for (int it = 0; it < 34; ++it) {
        float mid = 0.5f * (lo + hi);
        float ls = 0.f;
        for (int i = tid; i < TT; i += 1024) {
            float t = z[i] - mid;
            ls += (t > 0.f) ? t : 0.f;
        }
#pragma unroll
        for (int off = 32; off > 0; off >>= 1) ls += __shfl_xor(ls, off);
        if (lane == 0) red[wid] = ls;
        __syncthreads();
        if (tid == 0) {
            float s = 0.f;
            for (int i = 0; i < 16; ++i) s += red[i];
            bcast = s;
        }
        __syncthreads();
        if (bcast > 1.f) lo = mid; else hi = mid;
        // no extra barrier needed: next red[] write is ordered after the
        // barrier above, and tid0 finished reading red before releasing it
    }
    float tau = 0.5f * (lo + hi);
    float lsum = 0.f;
    for (int i = tid; i < TT; i += 1024) {
        float a = z[i] - tau;
        a = (a > 0.f) ? a : 0.f;
        a_out[(size_t)b * TT + i] = a;
        if (a > 0.f) {
            int p = atomicAdd(&cnt, 1);
            supp[b * TT + p] = i;
        }
        lsum += a;
    }
#pragma unroll
    for (int off = 32; off > 0; off >>= 1) lsum += __shfl_xor(lsum, off);
    if (lane == 0) red[wid] = lsum;
    __syncthreads();
    if (tid == 0) {
        float s = 0.f;
        for (int i = 0; i < 16; ++i) s += red[i];
        suma[b] = s;
        count[b] = cnt;
    }
}

// ------ Kernel 5: s = sum_t a*input[t]; out = s@Wv + suma*bv (per b) --------
__global__ __launch_bounds__(256) void k_out(const float* __restrict__ input,
                                             const float* __restrict__ a_out,
                                             const int* __restrict__ supp,
                                             const int* __restrict__ count,
                                             const float* __restrict__ suma,
                                             const float* __restrict__ Wv,
                                             const float* __restrict__ bv,
                                             float* __restrict__ out) {
    int b = blockIdx.x, tid = threadIdx.x;
    __shared__ float s_sh[DD];
    int cnt = count[b];
    float s = 0.f;
    for (int i = 0; i < cnt; ++i) {
        int t = supp[b * TT + i];
        float av = a_out[(size_t)b * TT + t];
        s += av * input[((size_t)b * TT + t) * DD + tid];
    }
    s_sh[tid] = s;
    __syncthreads();
    float acc = suma[b] * bv[tid];
    for (int d = 0; d < DD; ++d) acc += s_sh[d] * Wv[d * HH + tid];
    out[b * HH + tid] = acc;
}

extern "C" void kernel_launch(void* const* d_in, const int* in_sizes, int n_in,
                              void* d_out, int out_size, void* d_ws, size_t ws_size,
                              hipStream_t stream) {
    const float* input = (const float*)d_in[0];
    const int*   mask  = (const int*)d_in[1];
    const float* Wq    = (const float*)d_in[2];
    const float* bq    = (const float*)d_in[3];
    const float* Wk    = (const float*)d_in[4];
    const float* bk    = (const float*)d_in[5];
    const float* Wv    = (const float*)d_in[6];
    const float* bv    = (const float*)d_in[7];
    const float* rate  = (const float*)d_in[8];

    float* out   = (float*)d_out;            // (B,H)
    float* a_out = out + BB * HH;            // (B,T)

    float* ws      = (float*)d_ws;
    float* meansum = ws;                          // BB*DD
    float* wkq     = ws + 16384;                  // BB*DD
    float* ek      = ws + 32768;                  // BB
    float* suma    = ws + 32832;                  // BB
    float* e       = ws + 32896;                  // BB*TT
    int*   supp    = (int*)(ws + 32896 + BB * TT);
    int*   count   = (int*)(ws + 32896 + 2 * BB * TT);

    hipMemsetAsync(meansum, 0, BB * DD * sizeof(float), stream);
    k_colsum<<<dim3(BB, 32), 256, 0, stream>>>(input, meansum);
    k_small<<<BB, 256, 0, stream>>>(meansum, Wq, bq, Wk, bk, wkq, ek);
    k_scores<<<(BB * TT) / 4, 256, 0, stream>>>(input, wkq, ek, mask, rate, e);
    k_sparsemax<<<BB, 1024, 0, stream>>>(e, a_out, supp, count, suma);
    k_out<<<BB, 256, 0, stream>>>(input, a_out, supp, count, suma, Wv, bv, out);
}

// Round 2
// 172.202 us; speedup vs baseline: 1.0974x; 1.0974x over previous
//
#include <hip/hip_runtime.h>
#include <math.h>

#define BB 64
#define TT 4096
#define DD 256
#define HH 256
#define NEG_INF_F (-1e9f)

// ws layout (floats): meansum[BB*DD] @0 ; wkq[BB*DD] @16384 ; ek[BB] @32768 ;
//                     e[BB*TT] @32896

// ---------------- Kernel 1: column sums over T (for mean) -------------------
__global__ __launch_bounds__(256) void k_colsum(const float* __restrict__ input,
                                                float* __restrict__ meansum) {
    int b = blockIdx.x;
    int chunk = blockIdx.y;              // 32 chunks of 128 t each
    int tid = threadIdx.x;
    int tsub = tid >> 6;                 // 0..3
    int d4 = tid & 63;                   // float4 index over D
    const float4* base = (const float4*)(input + ((size_t)b * TT + (size_t)chunk * 128) * DD);
    float4 acc = make_float4(0.f, 0.f, 0.f, 0.f);
#pragma unroll 8
    for (int t = tsub; t < 128; t += 4) {
        float4 v = base[(size_t)t * 64 + d4];
        acc.x += v.x; acc.y += v.y; acc.z += v.z; acc.w += v.w;
    }
    __shared__ float4 sm[256];
    sm[tid] = acc;
    __syncthreads();
    if (tid < 64) {
        float4 a0 = sm[tid], a1 = sm[tid + 64], a2 = sm[tid + 128], a3 = sm[tid + 192];
        atomicAdd(&meansum[b * DD + tid * 4 + 0], a0.x + a1.x + a2.x + a3.x);
        atomicAdd(&meansum[b * DD + tid * 4 + 1], a0.y + a1.y + a2.y + a3.y);
        atomicAdd(&meansum[b * DD + tid * 4 + 2], a0.z + a1.z + a2.z + a3.z);
        atomicAdd(&meansum[b * DD + tid * 4 + 3], a0.w + a1.w + a2.w + a3.w);
    }
}

// ------------- Kernel 2: q = mean@Wq+bq ; wkq = Wk@q ; ek = bk.q ------------
__global__ __launch_bounds__(256) void k_small(const float* __restrict__ meansum,
                                               const float* __restrict__ Wq,
                                               const float* __restrict__ bq,
                                               const float* __restrict__ Wk,
                                               const float* __restrict__ bk,
                                               float* __restrict__ wkq,
                                               float* __restrict__ ek) {
    int b = blockIdx.x, tid = threadIdx.x;
    __shared__ __align__(16) float mr[DD];
    __shared__ __align__(16) float qsh[HH];
    __shared__ float red[4];
    mr[tid] = meansum[b * DD + tid] * (1.0f / (float)TT);
    __syncthreads();
    float acc = bq[tid];
#pragma unroll 8
    for (int d = 0; d < DD; ++d) acc += mr[d] * Wq[d * HH + tid];  // coalesced over tid
    qsh[tid] = acc;
    float p = bk[tid] * acc;
#pragma unroll
    for (int off = 32; off > 0; off >>= 1) p += __shfl_down(p, off);
    int wave = tid >> 6, lane = tid & 63;
    if (lane == 0) red[wave] = p;
    __syncthreads();
    if (tid == 0) ek[b] = red[0] + red[1] + red[2] + red[3];
    // wkq[d] = sum_h Wk[d][h]*q[h]: one wave per d -> coalesced Wk row reads
    const float4* q4 = (const float4*)qsh;
    float4 qv = q4[lane];
    for (int i = 0; i < 64; ++i) {
        int d = wave * 64 + i;
        float4 wv = ((const float4*)(Wk + (size_t)d * HH))[lane];
        float s = wv.x * qv.x + wv.y * qv.y + wv.z * qv.z + wv.w * qv.w;
#pragma unroll
        for (int off = 32; off > 0; off >>= 1) s += __shfl_down(s, off);
        if (lane == 0) wkq[b * DD + d] = s;
    }
}

// --------- Kernel 3: e[b,t] = input.wkq + ek, time-miss, mask ---------------
// Reversed block order: pass 1 left the TAIL of input resident in the 256 MiB
// Infinity Cache; reading tail-first turns cyclic eviction into LLC hits.
__global__ __launch_bounds__(256) void k_scores(const float* __restrict__ input,
                                                const float* __restrict__ wkq,
                                                const float* __restrict__ ek,
                                                const int* __restrict__ mask,
                                                const float* __restrict__ rate,
                                                float* __restrict__ e_out) {
    int job = (int)gridDim.x - 1 - (int)blockIdx.x;
    int b = job >> 7;                  // 128 blocks per b, 32 rows per block
    int t0 = (job & 127) << 5;
    int tid = threadIdx.x;
    __shared__ __align__(16) float wsh[DD];
    wsh[tid] = wkq[b * DD + tid];
    __syncthreads();
    int wave = tid >> 6, lane = tid & 63;
    float4 w = ((const float4*)wsh)[lane];
    float ekb = ek[b];
    int tbase = t0 + wave * 8;
    const float4* rows = (const float4*)(input + ((size_t)b * TT + tbase) * DD);
#pragma unroll
    for (int r = 0; r < 8; ++r) {
        float4 v = rows[(size_t)r * 64 + lane];
        float sum = v.x * w.x + v.y * w.y + v.z * w.z + v.w * w.w;
#pragma unroll
        for (int off = 32; off > 0; off >>= 1) sum += __shfl_down(sum, off);
        if (lane == 0) {
            int t = tbase + r;
            float e = sum + ekb;
            int m = mask[b * TT + t];
            if (m != 0) {
                float sg = 1.f / (1.f + expf(e));      // = 1 - sigmoid(e)
                e = e - rate[t] * log1pf(sg * (float)m);
            } else {
                e = NEG_INF_F;
            }
            e_out[b * TT + t] = e;
        }
    }
}

// ---- Kernel 4 (fused): sparsemax (Michelot) + sparse gather + @Wv + bv -----
__global__ __launch_bounds__(1024) void k_sparse_out(const float* __restrict__ e_in,
                                                     const float* __restrict__ input,
                                                     const float* __restrict__ Wv,
                                                     const float* __restrict__ bv,
                                                     float* __restrict__ out,
                                                     float* __restrict__ a_out) {
    int b = blockIdx.x, tid = threadIdx.x;
    int wave = tid >> 6, lane = tid & 63;
    __shared__ float za[TT];
    __shared__ int s_supp[TT];
    __shared__ __align__(16) float part[16 * DD];
    __shared__ __align__(16) float s_sh[DD];
    __shared__ float red[16], red2[16];
    __shared__ float f_b;
    __shared__ int i_b;
    __shared__ float suma_sh;
    __shared__ int cnt;

    const float* er = e_in + (size_t)b * TT;
    float z0 = er[tid], z1 = er[tid + 1024], z2 = er[tid + 2048], z3 = er[tid + 3072];
    float lmax = fmaxf(fmaxf(z0, z1), fmaxf(z2, z3));
#pragma unroll
    for (int off = 32; off > 0; off >>= 1) lmax = fmaxf(lmax, __shfl_xor(lmax, off));
    if (lane == 0) red[wave] = lmax;
    if (tid == 0) cnt = 0;
    __syncthreads();
    if (tid == 0) {
        float m = red[0];
        for (int i = 1; i < 16; ++i) m = fmaxf(m, red[i]);
        f_b = m;
    }
    __syncthreads();
    float mx = f_b;
    // clamp to -1: lossless (support always has z-zmax > -1), kills NEG_INF rows
    z0 = fmaxf(z0 - mx, -1.0f); z1 = fmaxf(z1 - mx, -1.0f);
    z2 = fmaxf(z2 - mx, -1.0f); z3 = fmaxf(z3 - mx, -1.0f);
    za[tid] = z0; za[tid + 1024] = z1; za[tid + 2048] = z2; za[tid + 3072] = z3;

    // Michelot fixed point: tau <- (sum_{z>tau} z - 1)/count; tau nondecreasing,
    // active set shrinks; count-stable => converged (same fixed point as sort).
    float tau = -1e30f;
    int prevc = -1;
    for (int it = 0; it < 32; ++it) {
        float s = 0.f, c = 0.f;
        if (z0 > tau) { s += z0; c += 1.f; }
        if (z1 > tau) { s += z1; c += 1.f; }
        if (z2 > tau) { s += z2; c += 1.f; }
        if (z3 > tau) { s += z3; c += 1.f; }
#pragma unroll
        for (int off = 32; off > 0; off >>= 1) {
            s += __shfl_xor(s, off);
            c += __shfl_xor(c, off);
        }
        if (lane == 0) { red[wave] = s; red2[wave] = c; }
        __syncthreads();
        if (tid == 0) {
            float ss = 0.f, cc = 0.f;
            for (int i = 0; i < 16; ++i) { ss += red[i]; cc += red2[i]; }
            f_b = (ss - 1.f) / cc;
            i_b = (int)cc;
        }
        __syncthreads();
        int c_all = i_b;         // uniform
        tau = f_b;
        bool done = (c_all == prevc);
        prevc = c_all;
        if (done) break;
    }

    // a, a_out, support list, suma
    float a0 = fmaxf(z0 - tau, 0.f), a1 = fmaxf(z1 - tau, 0.f);
    float a2 = fmaxf(z2 - tau, 0.f), a3 = fmaxf(z3 - tau, 0.f);
    float* ar = a_out + (size_t)b * TT;
    ar[tid] = a0; ar[tid + 1024] = a1; ar[tid + 2048] = a2; ar[tid + 3072] = a3;
    if (a0 > 0.f) s_supp[atomicAdd(&cnt, 1)] = tid;
    if (a1 > 0.f) s_supp[atomicAdd(&cnt, 1)] = tid + 1024;
    if (a2 > 0.f) s_supp[atomicAdd(&cnt, 1)] = tid + 2048;
    if (a3 > 0.f) s_supp[atomicAdd(&cnt, 1)] = tid + 3072;
    float lsum = a0 + a1 + a2 + a3;
#pragma unroll
    for (int off = 32; off > 0; off >>= 1) lsum += __shfl_xor(lsum, off);
    if (lane == 0) red[wave] = lsum;
    __syncthreads();
    if (tid == 0) {
        float ssum = 0.f;
        for (int i = 0; i < 16; ++i) ssum += red[i];
        suma_sh = ssum;
    }
    __syncthreads();

    // gather: s[d] = sum_{t in supp} a_t * input[b,t,d], waves split supp
    float4 acc = make_float4(0.f, 0.f, 0.f, 0.f);
    int cl = cnt;
    for (int i = wave; i < cl; i += 16) {
        int t = s_supp[i];
        float av = fmaxf(za[t] - tau, 0.f);
        float4 v = ((const float4*)(input + ((size_t)b * TT + t) * DD))[lane];
        acc.x += av * v.x; acc.y += av * v.y; acc.z += av * v.z; acc.w += av * v.w;
    }
    ((float4*)part)[wave * 64 + lane] = acc;
    __syncthreads();
    if (tid < 256) {
        float s = 0.f;
#pragma unroll
        for (int w = 0; w < 16; ++w) s += part[w * 256 + tid];
        s_sh[tid] = s;
    }
    __syncthreads();
    // out[h] = sum_d s[d]*Wv[d][h] + suma*bv[h]; 4 groups of 256 threads split d
    int h = tid & 255;
    int g = tid >> 8;                  // 0..3
    float o = 0.f;
#pragma unroll 8
    for (int d = g * 64; d < g * 64 + 64; ++d) o += s_sh[d] * Wv[(size_t)d * HH + h];
    part[g * 256 + h] = o;
    __syncthreads();
    if (tid < 256) {
        float o4 = part[tid] + part[256 + tid] + part[512 + tid] + part[768 + tid]
                 + suma_sh * bv[tid];
        out[b * HH + tid] = o4;
    }
}

extern "C" void kernel_launch(void* const* d_in, const int* in_sizes, int n_in,
                              void* d_out, int out_size, void* d_ws, size_t ws_size,
                              hipStream_t stream) {
    const float* input = (const float*)d_in[0];
    const int*   mask  = (const int*)d_in[1];
    const float* Wq    = (const float*)d_in[2];
    const float* bq    = (const float*)d_in[3];
    const float* Wk    = (const float*)d_in[4];
    const float* bk    = (const float*)d_in[5];
    const float* Wv    = (const float*)d_in[6];
    const float* bv    = (const float*)d_in[7];
    const float* rate  = (const float*)d_in[8];

    float* out   = (float*)d_out;            // (B,H)
    float* a_out = out + BB * HH;            // (B,T)

    float* ws      = (float*)d_ws;
    float* meansum = ws;                     // BB*DD
    float* wkq     = ws + 16384;             // BB*DD
    float* ek      = ws + 32768;             // BB
    float* e       = ws + 32896;             // BB*TT

    hipMemsetAsync(meansum, 0, BB * DD * sizeof(float), stream);
    k_colsum<<<dim3(BB, 32), 256, 0, stream>>>(input, meansum);
    k_small<<<BB, 256, 0, stream>>>(meansum, Wq, bq, Wk, bk, wkq, ek);
    k_scores<<<(BB * TT) / 32, 256, 0, stream>>>(input, wkq, ek, mask, rate, e);
    k_sparse_out<<<BB, 1024, 0, stream>>>(e, input, Wv, bv, out, a_out);
}

// Round 3
// 156.121 us; speedup vs baseline: 1.2104x; 1.1030x over previous
//
#include <hip/hip_runtime.h>
#include <math.h>

#define BB 64
#define TT 4096
#define DD 256
#define HH 256
#define NEG_INF_F (-1e9f)

// ws layout (floats):
//   partials[2048*256] @ 0        (2 MB)
//   wkq[BB*DD]         @ 524288
//   ek[BB]             @ 540672
//   e[BB*TT]           @ 540736

// ---------------- Kernel 1: per-chunk column partial sums -------------------
// grid (chunk=32, b=64): linear block order == ascending address order, so the
// LLC holds a clean ascending stream; k_scores then reads it descending.
__global__ __launch_bounds__(256) void k_colsum(const float* __restrict__ input,
                                                float* __restrict__ partials) {
    int chunk = blockIdx.x;              // 32 chunks of 128 t each
    int b = blockIdx.y;
    int tid = threadIdx.x;
    int tsub = tid >> 6;                 // 0..3
    int d4 = tid & 63;                   // float4 index over D
    const float4* base = (const float4*)(input + ((size_t)b * TT + (size_t)chunk * 128) * DD);
    float4 acc = make_float4(0.f, 0.f, 0.f, 0.f);
#pragma unroll 8
    for (int t = tsub; t < 128; t += 4) {
        float4 v = base[(size_t)t * 64 + d4];
        acc.x += v.x; acc.y += v.y; acc.z += v.z; acc.w += v.w;
    }
    __shared__ float4 sm[256];
    sm[tid] = acc;
    __syncthreads();
    if (tid < 64) {
        float4 a0 = sm[tid], a1 = sm[tid + 64], a2 = sm[tid + 128], a3 = sm[tid + 192];
        float4 r = make_float4(a0.x + a1.x + a2.x + a3.x,
                               a0.y + a1.y + a2.y + a3.y,
                               a0.z + a1.z + a2.z + a3.z,
                               a0.w + a1.w + a2.w + a3.w);
        ((float4*)(partials + ((size_t)b * 32 + chunk) * 256))[tid] = r;
    }
}

// --- Kernel 2: reduce partials -> mean; q = mean@Wq+bq ; wkq = Wk@q ; ek ----
__global__ __launch_bounds__(256) void k_small(const float* __restrict__ partials,
                                               const float* __restrict__ Wq,
                                               const float* __restrict__ bq,
                                               const float* __restrict__ Wk,
                                               const float* __restrict__ bk,
                                               float* __restrict__ wkq,
                                               float* __restrict__ ek) {
    int b = blockIdx.x, tid = threadIdx.x;
    int wave = tid >> 6, lane = tid & 63;
    __shared__ __align__(16) float mr[DD];
    __shared__ __align__(16) float qsh[HH];
    __shared__ float red[4];
    const float* pb = partials + (size_t)b * 32 * 256;
    float s = 0.f;
#pragma unroll
    for (int c = 0; c < 32; ++c) s += pb[c * 256 + tid];   // coalesced over tid
    mr[tid] = s * (1.0f / (float)TT);
    __syncthreads();
    float acc = bq[tid];
#pragma unroll 8
    for (int d = 0; d < DD; ++d) acc += mr[d] * Wq[d * HH + tid];  // coalesced
    qsh[tid] = acc;
    float p = bk[tid] * acc;
#pragma unroll
    for (int off = 32; off > 0; off >>= 1) p += __shfl_down(p, off);
    if (lane == 0) red[wave] = p;
    __syncthreads();                      // also publishes qsh
    if (tid == 0) ek[b] = red[0] + red[1] + red[2] + red[3];
    // wkq[d] = sum_h Wk[d][h]*q[h]: one wave per d -> coalesced Wk row reads
    float4 qv = ((const float4*)qsh)[lane];
    for (int i = 0; i < 64; ++i) {
        int d = wave * 64 + i;
        float4 wv = ((const float4*)(Wk + (size_t)d * HH))[lane];
        float t = wv.x * qv.x + wv.y * qv.y + wv.z * qv.z + wv.w * qv.w;
#pragma unroll
        for (int off = 32; off > 0; off >>= 1) t += __shfl_down(t, off);
        if (lane == 0) wkq[b * DD + d] = t;
    }
}

// --------- Kernel 3: e[b,t] = input.wkq + ek, time-miss, mask ---------------
// Descending address order: reads the freshest LLC lines first (pass 1 ended
// at the top address), giving near stack-distance-0 reuse of the 256 MiB LLC.
__global__ __launch_bounds__(256) void k_scores(const float* __restrict__ input,
                                                const float* __restrict__ wkq,
                                                const float* __restrict__ ek,
                                                const int* __restrict__ mask,
                                                const float* __restrict__ rate,
                                                float* __restrict__ e_out) {
    int job = (int)gridDim.x - 1 - (int)blockIdx.x;
    int b = job >> 6;                    // 64 blocks per b, 64 rows per block
    int t0 = (job & 63) << 6;
    int tid = threadIdx.x;
    int wave = tid >> 6, lane = tid & 63;
    __shared__ __align__(16) float wsh[DD];
    __shared__ float esh[64];
    wsh[tid] = wkq[b * DD + tid];
    __syncthreads();
    float4 w = ((const float4*)wsh)[lane];
    int tbase = t0 + wave * 16;
    const float4* rows = (const float4*)(input + ((size_t)b * TT + tbase) * DD);
#pragma unroll
    for (int r = 0; r < 16; ++r) {
        float4 v = rows[(size_t)r * 64 + lane];
        float sum = v.x * w.x + v.y * w.y + v.z * w.z + v.w * w.w;
#pragma unroll
        for (int off = 32; off > 0; off >>= 1) sum += __shfl_down(sum, off);
        if (lane == 0) esh[wave * 16 + r] = sum;
    }
    __syncthreads();
    if (tid < 64) {
        int t = t0 + tid;
        float e = esh[tid] + ek[b];
        int m = mask[b * TT + t];
        if (m != 0) {
            float sg = 1.f / (1.f + expf(e));      // = 1 - sigmoid(e)
            e = e - rate[t] * log1pf(sg * (float)m);
        } else {
            e = NEG_INF_F;
        }
        e_out[b * TT + t] = e;                     // coalesced 64-wide
    }
}

// ---- Kernel 4 (fused): sparsemax (seeded Michelot) + gather + @Wv + bv -----
__global__ __launch_bounds__(1024) void k_fin(const float* __restrict__ e_in,
                                              const float* __restrict__ input,
                                              const float* __restrict__ Wv,
                                              const float* __restrict__ bv,
                                              float* __restrict__ out,
                                              float* __restrict__ a_out) {
    int b = blockIdx.x, tid = threadIdx.x;
    int wave = tid >> 6, lane = tid & 63;
    __shared__ float za[TT];                       // 16 KB
    __shared__ int s_supp[TT];                     // 16 KB (worst case all-active)
    __shared__ __align__(16) float part[16 * DD];  // 16 KB
    __shared__ __align__(16) float s_sh[DD];
    __shared__ float redM[16];
    __shared__ float redS[2][16], redC[2][16];
    __shared__ int cnt;

    const float* er = e_in + (size_t)b * TT;
    float z0 = er[tid], z1 = er[tid + 1024], z2 = er[tid + 2048], z3 = er[tid + 3072];
    float lmax = fmaxf(fmaxf(z0, z1), fmaxf(z2, z3));
#pragma unroll
    for (int off = 32; off > 0; off >>= 1) lmax = fmaxf(lmax, __shfl_xor(lmax, off));
    if (lane == 0) redM[wave] = lmax;
    if (tid == 0) cnt = 0;
    __syncthreads();
    float mx = redM[0];
#pragma unroll
    for (int i = 1; i < 16; ++i) mx = fmaxf(mx, redM[i]);  // uniform LDS broadcast
    // clamp to -1: lossless (support always has z-zmax > -1), kills NEG_INF rows
    z0 = fmaxf(z0 - mx, -1.0f); z1 = fmaxf(z1 - mx, -1.0f);
    z2 = fmaxf(z2 - mx, -1.0f); z3 = fmaxf(z3 - mx, -1.0f);
    za[tid] = z0; za[tid + 1024] = z1; za[tid + 2048] = z2; za[tid + 3072] = z3;

    // Michelot fixed point seeded at tau=-1 (support subset of {z > zmax-1}):
    // active set starts ~= final support -> ~2-4 iterations. One barrier/iter
    // via double-buffered reduction arrays (WAR-safe).
    float tau = -1.0f;
    int prevc = -1;
    for (int it = 0; it < 32; ++it) {
        int pb = it & 1;
        float s = 0.f, c = 0.f;
        if (z0 > tau) { s += z0; c += 1.f; }
        if (z1 > tau) { s += z1; c += 1.f; }
        if (z2 > tau) { s += z2; c += 1.f; }
        if (z3 > tau) { s += z3; c += 1.f; }
#pragma unroll
        for (int off = 32; off > 0; off >>= 1) {
            s += __shfl_xor(s, off);
            c += __shfl_xor(c, off);
        }
        if (lane == 0) { redS[pb][wave] = s; redC[pb][wave] = c; }
        __syncthreads();
        float ss = 0.f, cc = 0.f;
#pragma unroll
        for (int i = 0; i < 16; ++i) { ss += redS[pb][i]; cc += redC[pb][i]; }
        tau = (ss - 1.f) / cc;            // identical across all threads
        int ci = (int)cc;
        if (ci == prevc) break;           // set stable => fixed point
        prevc = ci;
    }

    // a, a_out, support list, suma
    float a0 = fmaxf(z0 - tau, 0.f), a1 = fmaxf(z1 - tau, 0.f);
    float a2 = fmaxf(z2 - tau, 0.f), a3 = fmaxf(z3 - tau, 0.f);
    float* ar = a_out + (size_t)b * TT;
    ar[tid] = a0; ar[tid + 1024] = a1; ar[tid + 2048] = a2; ar[tid + 3072] = a3;
    if (a0 > 0.f) s_supp[atomicAdd(&cnt, 1)] = tid;
    if (a1 > 0.f) s_supp[atomicAdd(&cnt, 1)] = tid + 1024;
    if (a2 > 0.f) s_supp[atomicAdd(&cnt, 1)] = tid + 2048;
    if (a3 > 0.f) s_supp[atomicAdd(&cnt, 1)] = tid + 3072;
    float lsum = a0 + a1 + a2 + a3;
#pragma unroll
    for (int off = 32; off > 0; off >>= 1) lsum += __shfl_xor(lsum, off);
    if (lane == 0) redM[wave] = lsum;
    __syncthreads();                      // publishes redM, s_supp, cnt
    float suma = 0.f;
#pragma unroll
    for (int i = 0; i < 16; ++i) suma += redM[i];  // uniform

    // gather: s[d] = sum_{t in supp} a_t * input[b,t,d], waves split supp
    float4 acc = make_float4(0.f, 0.f, 0.f, 0.f);
    int cl = cnt;
    for (int i = wave; i < cl; i += 16) {
        int t = s_supp[i];
        float av = fmaxf(za[t] - tau, 0.f);
        float4 v = ((const float4*)(input + ((size_t)b * TT + t) * DD))[lane];
        acc.x += av * v.x; acc.y += av * v.y; acc.z += av * v.z; acc.w += av * v.w;
    }
    ((float4*)part)[wave * 64 + lane] = acc;
    __syncthreads();
    if (tid < 256) {
        float s = 0.f;
#pragma unroll
        for (int w = 0; w < 16; ++w) s += part[w * 256 + tid];
        s_sh[tid] = s;
    }
    __syncthreads();
    // out[h] = sum_d s[d]*Wv[d][h] + suma*bv[h]; 4 groups of 256 threads split d
    int h = tid & 255;
    int g = tid >> 8;                  // 0..3
    float o = 0.f;
#pragma unroll 8
    for (int d = g * 64; d < g * 64 + 64; ++d) o += s_sh[d] * Wv[(size_t)d * HH + h];
    part[g * 256 + h] = o;
    __syncthreads();
    if (tid < 256) {
        float o4 = part[tid] + part[256 + tid] + part[512 + tid] + part[768 + tid]
                 + suma * bv[tid];
        out[b * HH + tid] = o4;
    }
}

extern "C" void kernel_launch(void* const* d_in, const int* in_sizes, int n_in,
                              void* d_out, int out_size, void* d_ws, size_t ws_size,
                              hipStream_t stream) {
    const float* input = (const float*)d_in[0];
    const int*   mask  = (const int*)d_in[1];
    const float* Wq    = (const float*)d_in[2];
    const float* bq    = (const float*)d_in[3];
    const float* Wk    = (const float*)d_in[4];
    const float* bk    = (const float*)d_in[5];
    const float* Wv    = (const float*)d_in[6];
    const float* bv    = (const float*)d_in[7];
    const float* rate  = (const float*)d_in[8];

    float* out   = (float*)d_out;            // (B,H)
    float* a_out = out + BB * HH;            // (B,T)

    float* ws       = (float*)d_ws;
    float* partials = ws;                    // 2048*256
    float* wkq      = ws + 524288;           // BB*DD
    float* ek       = ws + 540672;           // BB
    float* e        = ws + 540736;           // BB*TT

    k_colsum<<<dim3(32, BB), 256, 0, stream>>>(input, partials);
    k_small<<<BB, 256, 0, stream>>>(partials, Wq, bq, Wk, bk, wkq, ek);
    k_scores<<<(BB * TT) / 64, 256, 0, stream>>>(input, wkq, ek, mask, rate, e);
    k_fin<<<BB, 1024, 0, stream>>>(e, input, Wv, bv, out, a_out);
}